// Round 3
// baseline (699.535 us; speedup 1.0000x reference)
//
#include <hip/hip_runtime.h>
#include <hip/hip_bf16.h>

typedef __bf16 bf16_t;
typedef __attribute__((ext_vector_type(8))) __bf16 bf16x8;
typedef __attribute__((ext_vector_type(4))) __bf16 bf16x4;
typedef __attribute__((ext_vector_type(4))) float f32x4;

// ---------------- problem constants ----------------
#define LQ 144           // window length (2*6*12)
#define CDIM 192
#define NHEADS 6
#define HD 32
#define NWIN 960         // total windows (64 nw-groups * 15 w_wins)
#define WWINS 15
#define MROWS 138240     // 960*144
#define SCALE_Q 0.17677669529663687f

// workspace offsets (bytes)
#define OFF_QKV   0ull                    // 138240*576 bf16 = 159,252,480
#define OFF_ATTN  159252480ull            // 138240*192 bf16 = 53,084,160
#define OFF_BIAS  212336640ull            // 64*6*144*144 f32 = 31,850,496
#define OFF_W1T   244187136ull            // 576*192 bf16
#define OFF_W2T   244408320ull            // 192*192 bf16

// ---------------- prep: transpose+convert weights ----------------
__global__ void prep_w_kernel(const float* __restrict__ W1, const float* __restrict__ W2,
                              bf16_t* __restrict__ w1t, bf16_t* __restrict__ w2t) {
    int idx = blockIdx.x * 256 + threadIdx.x;
    if (idx < 576 * 192) {             // w1t[n][k] = W1[k][n]
        int n = idx / 192, k = idx % 192;
        w1t[idx] = (bf16_t)W1[k * 576 + n];
    }
    if (idx < 192 * 192) {             // w2t[n][k] = W2[k][n]
        int n = idx / 192, k = idx % 192;
        w2t[idx] = (bf16_t)W2[k * 192 + n];
    }
}

// ---------------- bias gather: bias_full[nw][h][q][m] ----------------
__global__ void bias_gather_kernel(const float* __restrict__ table, const int* __restrict__ pi,
                                   float* __restrict__ bias_full) {
    int idx = blockIdx.x * 256 + threadIdx.x;   // grid sized exactly 64*6*144*144
    int m = idx % LQ;
    int t = idx / LQ;
    int q = t % LQ; t /= LQ;
    int hh = t % NHEADS;
    int nw = t / NHEADS;
    int p = pi[q * LQ + m];
    bias_full[idx] = table[(p * 64 + nw) * NHEADS + hh];
}

// ---------------- GEMM1: qkv = (x @ W1 + b1), q-part scaled; bf16 out ----------------
// block 256 thr (4 waves 2x2), tile 128x64, BK=64, K=192
__global__ __launch_bounds__(256) void gemm1_kernel(
    const float* __restrict__ X, const bf16_t* __restrict__ W1t,
    const float* __restrict__ b1, bf16_t* __restrict__ qkv) {
    __shared__ bf16_t As[128 * 72];
    __shared__ bf16_t Bs[64 * 72];
    const int tid = threadIdx.x;
    const int row0 = blockIdx.x * 128;
    const int n0 = blockIdx.y * 64;
    const int lane = tid & 63, wid = tid >> 6;
    const int wr = wid >> 1, wc = wid & 1;
    const int l15 = lane & 15, g = lane >> 4;

    f32x4 acc[4][2];
#pragma unroll
    for (int a = 0; a < 4; ++a)
#pragma unroll
        for (int b = 0; b < 2; ++b) acc[a][b] = (f32x4){0.f, 0.f, 0.f, 0.f};

    for (int kk = 0; kk < 3; ++kk) {
        {   // stage A (fp32 -> bf16): 128 rows x 64 k
            int row = tid >> 1, half = tid & 1;
            const float* src = X + (size_t)(row0 + row) * 192 + kk * 64 + half * 32;
            bf16_t* dst = &As[row * 72 + half * 32];
#pragma unroll
            for (int j = 0; j < 4; ++j) {
                f32x4 v0 = ((const f32x4*)src)[2 * j];
                f32x4 v1 = ((const f32x4*)src)[2 * j + 1];
                bf16x8 w;
#pragma unroll
                for (int r = 0; r < 4; ++r) { w[r] = (bf16_t)v0[r]; w[4 + r] = (bf16_t)v1[r]; }
                *(bf16x8*)(dst + 8 * j) = w;
            }
        }
        {   // stage B (already bf16, [n][k] layout): 64 n x 64 k
            int n = tid >> 2, qtr = tid & 3;
            const bf16_t* src = W1t + (size_t)(n0 + n) * 192 + kk * 64 + qtr * 16;
            bf16x8 v0 = ((const bf16x8*)src)[0];
            bf16x8 v1 = ((const bf16x8*)src)[1];
            *(bf16x8*)&Bs[n * 72 + qtr * 16] = v0;
            *(bf16x8*)&Bs[n * 72 + qtr * 16 + 8] = v1;
        }
        __syncthreads();
#pragma unroll
        for (int ks = 0; ks < 2; ++ks) {
            bf16x8 af[4], bfr[2];
#pragma unroll
            for (int rt = 0; rt < 4; ++rt)
                af[rt] = *(const bf16x8*)&As[(wr * 64 + rt * 16 + l15) * 72 + ks * 32 + 8 * g];
#pragma unroll
            for (int ct = 0; ct < 2; ++ct)
                bfr[ct] = *(const bf16x8*)&Bs[(wc * 32 + ct * 16 + l15) * 72 + ks * 32 + 8 * g];
#pragma unroll
            for (int rt = 0; rt < 4; ++rt)
#pragma unroll
                for (int ct = 0; ct < 2; ++ct)
                    acc[rt][ct] = __builtin_amdgcn_mfma_f32_16x16x32_bf16(af[rt], bfr[ct], acc[rt][ct], 0, 0, 0);
        }
        __syncthreads();
    }
#pragma unroll
    for (int ct = 0; ct < 2; ++ct) {
        int n = n0 + wc * 32 + ct * 16 + l15;
        float bv = b1[n];
        float sc = (n < 192) ? SCALE_Q : 1.0f;   // q = (x@W1+b1)*scale
#pragma unroll
        for (int rt = 0; rt < 4; ++rt) {
#pragma unroll
            for (int r = 0; r < 4; ++r) {
                int m = row0 + wr * 64 + rt * 16 + 4 * g + r;
                qkv[(size_t)m * 576 + n] = (bf16_t)((acc[rt][ct][r] + bv) * sc);
            }
        }
    }
}

// ---------------- attention: 1 block per (window, head), 3 waves ----------------
// S^T = K*Q^T (so P LDS writes are contiguous), softmax per q-row,
// PV as out^T = V^T * P^T (both fragments contiguous b128 reads).
#define QKP 40     // Qs/Ks pitch (bf16)
#define PP 168     // P / Vt pitch (bf16), m padded 144->160
__global__ __launch_bounds__(192) void attn_kernel(
    const bf16_t* __restrict__ qkv, const float* __restrict__ mask,
    const float* __restrict__ bias_full, bf16_t* __restrict__ attn_o) {
    __shared__ bf16_t Vt[32 * PP];       // V^T [d][m], m zero-padded to 160
    __shared__ bf16_t Pb[144 * PP];      // P  [q][m]; Qs/Ks alias this region in phase 1
    bf16_t* Qs = Pb;                     // [144][QKP]
    bf16_t* Ks = Pb + 144 * QKP;

    const int tid = threadIdx.x;
    const int bid = blockIdx.x;
    const int wi = bid / NHEADS;
    const int h = bid % NHEADS;
    const int gb = (wi / WWINS) * NHEADS + h;     // bias group (nw*6+h)

    const bf16_t* base = qkv + (size_t)wi * (LQ * 576);
#pragma unroll
    for (int it = 0; it < 3; ++it) {
        int idx = tid + it * 192;
        int l = idx >> 2, sg = (idx & 3) * 8;
        const bf16_t* p = base + l * 576 + h * 32 + sg;
        bf16x8 vq = *(const bf16x8*)(p);
        bf16x8 vk = *(const bf16x8*)(p + 192);
        bf16x8 vv = *(const bf16x8*)(p + 384);
        *(bf16x8*)&Qs[l * QKP + sg] = vq;
        *(bf16x8*)&Ks[l * QKP + sg] = vk;
#pragma unroll
        for (int j = 0; j < 8; ++j) Vt[(sg + j) * PP + l] = vv[j];
    }
    for (int idx = tid; idx < 512; idx += 192)    // zero Vt tail m=144..159
        Vt[(idx >> 4) * PP + 144 + (idx & 15)] = (bf16_t)0.f;
    __syncthreads();

    const int lane = tid & 63;
    const int wid = tid >> 6;      // 0..2, owns q rows [wid*48, wid*48+48)
    const int l15 = lane & 15;
    const int g = lane >> 4;
    const int q0w = wid * 48;

    bf16x8 qf[3];
#pragma unroll
    for (int qt = 0; qt < 3; ++qt)
        qf[qt] = *(const bf16x8*)&Qs[(q0w + qt * 16 + l15) * QKP + 8 * g];

    f32x4 acc[3][9];
#pragma unroll
    for (int qt = 0; qt < 3; ++qt)
#pragma unroll
        for (int mt = 0; mt < 9; ++mt) acc[qt][mt] = (f32x4){0.f, 0.f, 0.f, 0.f};

#pragma unroll
    for (int mt = 0; mt < 9; ++mt) {
        bf16x8 kf = *(const bf16x8*)&Ks[(mt * 16 + l15) * QKP + 8 * g];
#pragma unroll
        for (int qt = 0; qt < 3; ++qt)
            acc[qt][mt] = __builtin_amdgcn_mfma_f32_16x16x32_bf16(kf, qf[qt], acc[qt][mt], 0, 0, 0);
    }
    // lane holds S^T tile elems: q = q0w+qt*16+l15 (fixed/lane), m = mt*16+4g+r
#pragma unroll
    for (int qt = 0; qt < 3; ++qt) {
        int q = q0w + qt * 16 + l15;
        const f32x4* brow = (const f32x4*)(bias_full + ((size_t)gb * LQ + q) * LQ);
        const f32x4* mrow = (const f32x4*)(mask + ((size_t)wi * LQ + q) * LQ);
#pragma unroll
        for (int mt = 0; mt < 9; ++mt) {
            f32x4 bv = brow[mt * 4 + g];
            f32x4 mv = mrow[mt * 4 + g];
            acc[qt][mt] += bv + mv;
        }
    }
    __syncthreads();    // all waves done reading Qs/Ks before P overwrites

#pragma unroll
    for (int qt = 0; qt < 3; ++qt) {
        float mx = -3.0e38f;
#pragma unroll
        for (int mt = 0; mt < 9; ++mt)
#pragma unroll
            for (int r = 0; r < 4; ++r) mx = fmaxf(mx, acc[qt][mt][r]);
        mx = fmaxf(mx, __shfl_xor(mx, 16));
        mx = fmaxf(mx, __shfl_xor(mx, 32));
        float sum = 0.f;
#pragma unroll
        for (int mt = 0; mt < 9; ++mt)
#pragma unroll
            for (int r = 0; r < 4; ++r) {
                float e = __expf(acc[qt][mt][r] - mx);
                acc[qt][mt][r] = e;
                sum += e;
            }
        sum += __shfl_xor(sum, 16);
        sum += __shfl_xor(sum, 32);
        float inv = 1.f / sum;
        int q = q0w + qt * 16 + l15;
#pragma unroll
        for (int mt = 0; mt < 9; ++mt) {
            bf16x4 pk;
#pragma unroll
            for (int r = 0; r < 4; ++r) pk[r] = (bf16_t)(acc[qt][mt][r] * inv);
            *(bf16x4*)&Pb[q * PP + mt * 16 + 4 * g] = pk;   // contiguous 4 m's
        }
    }
    {   // zero P tail m=144..159 for this wave's rows
        bf16x4 z; 
#pragma unroll
        for (int r = 0; r < 4; ++r) z[r] = (bf16_t)0.f;
#pragma unroll
        for (int u = 0; u < 3; ++u) {
            int uu = lane + u * 64;
            int row = q0w + (uu >> 2);
            *(bf16x4*)&Pb[row * PP + 144 + (uu & 3) * 4] = z;
        }
    }
    __syncthreads();

    // PV: out^T[d][q] = sum_m V^T[d][m] * P^T[m][q], 5 m-chunks of 32 (padded)
    f32x4 o[2][3];
#pragma unroll
    for (int dt = 0; dt < 2; ++dt)
#pragma unroll
        for (int qt = 0; qt < 3; ++qt) o[dt][qt] = (f32x4){0.f, 0.f, 0.f, 0.f};
#pragma unroll
    for (int mc = 0; mc < 5; ++mc) {
        bf16x8 av[2], bp[3];
#pragma unroll
        for (int dt = 0; dt < 2; ++dt)
            av[dt] = *(const bf16x8*)&Vt[(dt * 16 + l15) * PP + mc * 32 + 8 * g];
#pragma unroll
        for (int qt = 0; qt < 3; ++qt)
            bp[qt] = *(const bf16x8*)&Pb[(q0w + qt * 16 + l15) * PP + mc * 32 + 8 * g];
#pragma unroll
        for (int dt = 0; dt < 2; ++dt)
#pragma unroll
            for (int qt = 0; qt < 3; ++qt)
                o[dt][qt] = __builtin_amdgcn_mfma_f32_16x16x32_bf16(av[dt], bp[qt], o[dt][qt], 0, 0, 0);
    }
    // C layout: q = l15 (col), d = 4g+r (row) -> 4 consecutive d: 8B stores
#pragma unroll
    for (int dt = 0; dt < 2; ++dt)
#pragma unroll
        for (int qt = 0; qt < 3; ++qt) {
            int q = q0w + qt * 16 + l15;
            int d0 = dt * 16 + 4 * g;
            bf16x4 pk;
#pragma unroll
            for (int r = 0; r < 4; ++r) pk[r] = (bf16_t)o[dt][qt][r];
            *(bf16x4*)(attn_o + ((size_t)wi * LQ + q) * CDIM + h * HD + d0) = pk;
        }
}

// ---------------- GEMM2: out = attn_o @ W2 + b2 (fp32 out) ----------------
__global__ __launch_bounds__(256) void gemm2_kernel(
    const bf16_t* __restrict__ A, const bf16_t* __restrict__ W2t,
    const float* __restrict__ b2, float* __restrict__ out) {
    __shared__ bf16_t As[128 * 72];
    __shared__ bf16_t Bs[64 * 72];
    const int tid = threadIdx.x;
    const int row0 = blockIdx.x * 128;
    const int n0 = blockIdx.y * 64;
    const int lane = tid & 63, wid = tid >> 6;
    const int wr = wid >> 1, wc = wid & 1;
    const int l15 = lane & 15, g = lane >> 4;

    f32x4 acc[4][2];
#pragma unroll
    for (int a = 0; a < 4; ++a)
#pragma unroll
        for (int b = 0; b < 2; ++b) acc[a][b] = (f32x4){0.f, 0.f, 0.f, 0.f};

    for (int kk = 0; kk < 3; ++kk) {
        {
            int row = tid >> 1, half = tid & 1;
            const bf16_t* src = A + (size_t)(row0 + row) * 192 + kk * 64 + half * 32;
            bf16_t* dst = &As[row * 72 + half * 32];
            bf16x8 v0 = ((const bf16x8*)src)[0];
            bf16x8 v1 = ((const bf16x8*)src)[1];
            bf16x8 v2 = ((const bf16x8*)src)[2];
            bf16x8 v3 = ((const bf16x8*)src)[3];
            *(bf16x8*)(dst) = v0; *(bf16x8*)(dst + 8) = v1;
            *(bf16x8*)(dst + 16) = v2; *(bf16x8*)(dst + 24) = v3;
        }
        {
            int n = tid >> 2, qtr = tid & 3;
            const bf16_t* src = W2t + (size_t)(n0 + n) * 192 + kk * 64 + qtr * 16;
            bf16x8 v0 = ((const bf16x8*)src)[0];
            bf16x8 v1 = ((const bf16x8*)src)[1];
            *(bf16x8*)&Bs[n * 72 + qtr * 16] = v0;
            *(bf16x8*)&Bs[n * 72 + qtr * 16 + 8] = v1;
        }
        __syncthreads();
#pragma unroll
        for (int ks = 0; ks < 2; ++ks) {
            bf16x8 af[4], bfr[2];
#pragma unroll
            for (int rt = 0; rt < 4; ++rt)
                af[rt] = *(const bf16x8*)&As[(wr * 64 + rt * 16 + l15) * 72 + ks * 32 + 8 * g];
#pragma unroll
            for (int ct = 0; ct < 2; ++ct)
                bfr[ct] = *(const bf16x8*)&Bs[(wc * 32 + ct * 16 + l15) * 72 + ks * 32 + 8 * g];
#pragma unroll
            for (int rt = 0; rt < 4; ++rt)
#pragma unroll
                for (int ct = 0; ct < 2; ++ct)
                    acc[rt][ct] = __builtin_amdgcn_mfma_f32_16x16x32_bf16(af[rt], bfr[ct], acc[rt][ct], 0, 0, 0);
        }
        __syncthreads();
    }
#pragma unroll
    for (int ct = 0; ct < 2; ++ct) {
        int n = n0 + wc * 32 + ct * 16 + l15;
        float bv = b2[n];
#pragma unroll
        for (int rt = 0; rt < 4; ++rt) {
#pragma unroll
            for (int r = 0; r < 4; ++r) {
                int m = row0 + wr * 64 + rt * 16 + 4 * g + r;
                out[(size_t)m * 192 + n] = acc[rt][ct][r] + bv;
            }
        }
    }
}

// ---------------- launch ----------------
extern "C" void kernel_launch(void* const* d_in, const int* in_sizes, int n_in,
                              void* d_out, int out_size, void* d_ws, size_t ws_size,
                              hipStream_t stream) {
    const float* x = (const float*)d_in[0];
    const float* mask = (const float*)d_in[1];
    const float* W1 = (const float*)d_in[2];
    const float* b1 = (const float*)d_in[3];
    const float* W2 = (const float*)d_in[4];
    const float* b2 = (const float*)d_in[5];
    const float* table = (const float*)d_in[6];
    const int* pi = (const int*)d_in[7];
    float* out = (float*)d_out;

    char* ws = (char*)d_ws;
    bf16_t* qkv = (bf16_t*)(ws + OFF_QKV);
    bf16_t* attn_o = (bf16_t*)(ws + OFF_ATTN);
    float* bias_full = (float*)(ws + OFF_BIAS);
    bf16_t* w1t = (bf16_t*)(ws + OFF_W1T);
    bf16_t* w2t = (bf16_t*)(ws + OFF_W2T);

    prep_w_kernel<<<dim3(432), dim3(256), 0, stream>>>(W1, W2, w1t, w2t);
    bias_gather_kernel<<<dim3(31104), dim3(256), 0, stream>>>(table, pi, bias_full);
    gemm1_kernel<<<dim3(1080, 9), dim3(256), 0, stream>>>(x, w1t, b1, qkv);
    attn_kernel<<<dim3(5760), dim3(192), 0, stream>>>(qkv, mask, bias_full, attn_o);
    gemm2_kernel<<<dim3(1080, 3), dim3(256), 0, stream>>>(attn_o, w2t, b2, out);
}

// Round 5
// 654.501 us; speedup vs baseline: 1.0688x; 1.0688x over previous
//
#include <hip/hip_runtime.h>
#include <hip/hip_bf16.h>

typedef __bf16 bf16_t;
typedef __attribute__((ext_vector_type(8))) __bf16 bf16x8;
typedef __attribute__((ext_vector_type(4))) __bf16 bf16x4;
typedef __attribute__((ext_vector_type(4))) float f32x4;

// ---------------- problem constants ----------------
#define LQ 144           // window length (2*6*12)
#define CDIM 192
#define NHEADS 6
#define HD 32
#define NWIN 960         // total windows (64 nw-groups * 15 w_wins)
#define WWINS 15
#define MROWS 138240     // 960*144
#define SCALE_Q 0.17677669529663687f

// workspace offsets (bytes)
#define OFF_QKV   0ull                    // 138240*576 bf16 = 159,252,480
#define OFF_ATTN  159252480ull            // 138240*192 bf16 = 53,084,160
#define OFF_BIAS  212336640ull            // 64*6*144*144 f32 = 31,850,496
#define OFF_W1T   244187136ull            // 576*192 bf16
#define OFF_W2T   244408320ull            // 192*192 bf16

// ---------------- prep: transpose+convert weights ----------------
__global__ void prep_w_kernel(const float* __restrict__ W1, const float* __restrict__ W2,
                              bf16_t* __restrict__ w1t, bf16_t* __restrict__ w2t) {
    int idx = blockIdx.x * 256 + threadIdx.x;
    if (idx < 576 * 192) {             // w1t[n][k] = W1[k][n]
        int n = idx / 192, k = idx % 192;
        w1t[idx] = (bf16_t)W1[k * 576 + n];
    }
    if (idx < 192 * 192) {             // w2t[n][k] = W2[k][n]
        int n = idx / 192, k = idx % 192;
        w2t[idx] = (bf16_t)W2[k * 192 + n];
    }
}

// ---------------- bias gather: bias_full[nw][h][q][m] ----------------
__global__ void bias_gather_kernel(const float* __restrict__ table, const int* __restrict__ pi,
                                   float* __restrict__ bias_full) {
    int idx = blockIdx.x * 256 + threadIdx.x;   // grid sized exactly 64*6*144*144
    int m = idx % LQ;
    int t = idx / LQ;
    int q = t % LQ; t /= LQ;
    int hh = t % NHEADS;
    int nw = t / NHEADS;
    int p = pi[q * LQ + m];
    bias_full[idx] = table[(p * 64 + nw) * NHEADS + hh];
}

// ---------------- GEMM1: qkv = (x @ W1 + b1), q-part scaled; bf16 out ----------------
// block 256 thr (4 waves 2x2), tile 128x64, BK=64, K=192
__global__ __launch_bounds__(256) void gemm1_kernel(
    const float* __restrict__ X, const bf16_t* __restrict__ W1t,
    const float* __restrict__ b1, bf16_t* __restrict__ qkv) {
    __shared__ bf16_t As[128 * 72];
    __shared__ bf16_t Bs[64 * 72];
    const int tid = threadIdx.x;
    const int row0 = blockIdx.x * 128;
    const int n0 = blockIdx.y * 64;
    const int lane = tid & 63, wid = tid >> 6;
    const int wr = wid >> 1, wc = wid & 1;
    const int l15 = lane & 15, g = lane >> 4;

    f32x4 acc[4][2];
#pragma unroll
    for (int a = 0; a < 4; ++a)
#pragma unroll
        for (int b = 0; b < 2; ++b) acc[a][b] = (f32x4){0.f, 0.f, 0.f, 0.f};

    for (int kk = 0; kk < 3; ++kk) {
        {   // stage A (fp32 -> bf16): 128 rows x 64 k
            int row = tid >> 1, half = tid & 1;
            const float* src = X + (size_t)(row0 + row) * 192 + kk * 64 + half * 32;
            bf16_t* dst = &As[row * 72 + half * 32];
#pragma unroll
            for (int j = 0; j < 4; ++j) {
                f32x4 v0 = ((const f32x4*)src)[2 * j];
                f32x4 v1 = ((const f32x4*)src)[2 * j + 1];
                bf16x8 w;
#pragma unroll
                for (int r = 0; r < 4; ++r) { w[r] = (bf16_t)v0[r]; w[4 + r] = (bf16_t)v1[r]; }
                *(bf16x8*)(dst + 8 * j) = w;
            }
        }
        {   // stage B (already bf16, [n][k] layout): 64 n x 64 k
            int n = tid >> 2, qtr = tid & 3;
            const bf16_t* src = W1t + (size_t)(n0 + n) * 192 + kk * 64 + qtr * 16;
            bf16x8 v0 = ((const bf16x8*)src)[0];
            bf16x8 v1 = ((const bf16x8*)src)[1];
            *(bf16x8*)&Bs[n * 72 + qtr * 16] = v0;
            *(bf16x8*)&Bs[n * 72 + qtr * 16 + 8] = v1;
        }
        __syncthreads();
#pragma unroll
        for (int ks = 0; ks < 2; ++ks) {
            bf16x8 af[4], bfr[2];
#pragma unroll
            for (int rt = 0; rt < 4; ++rt)
                af[rt] = *(const bf16x8*)&As[(wr * 64 + rt * 16 + l15) * 72 + ks * 32 + 8 * g];
#pragma unroll
            for (int ct = 0; ct < 2; ++ct)
                bfr[ct] = *(const bf16x8*)&Bs[(wc * 32 + ct * 16 + l15) * 72 + ks * 32 + 8 * g];
#pragma unroll
            for (int rt = 0; rt < 4; ++rt)
#pragma unroll
                for (int ct = 0; ct < 2; ++ct)
                    acc[rt][ct] = __builtin_amdgcn_mfma_f32_16x16x32_bf16(af[rt], bfr[ct], acc[rt][ct], 0, 0, 0);
        }
        __syncthreads();
    }
#pragma unroll
    for (int ct = 0; ct < 2; ++ct) {
        int n = n0 + wc * 32 + ct * 16 + l15;
        float bv = b1[n];
        float sc = (n < 192) ? SCALE_Q : 1.0f;   // q = (x@W1+b1)*scale
#pragma unroll
        for (int rt = 0; rt < 4; ++rt) {
#pragma unroll
            for (int r = 0; r < 4; ++r) {
                int m = row0 + wr * 64 + rt * 16 + 4 * g + r;
                qkv[(size_t)m * 576 + n] = (bf16_t)((acc[rt][ct][r] + bv) * sc);
            }
        }
    }
}

// ---------------- attention: 1 block per (window, head), 9 waves (576 thr) ----------------
// Each wave owns ONE 16-row q-tile. Q fragment loaded directly from global
// (no Q staging). S^T = K*Q^T; softmax per q-row; PV as out^T = V^T * P^T.
// LDS: Pb[144][PP] (K stage aliases its head) + Vt[32][PP] = 59.1 KB -> 2 blk/CU
// = 18 waves/CU (was 6 with the 3-wave version: occupancy was the bottleneck,
// Occ 16.9% / VALUBusy 14% / MfmaUtil 2.4%).
#define KP 40      // Ks pitch (bf16): 80 B rows -> 2-way b128 bank aliasing (free)
#define PP 168     // P / Vt pitch (bf16), m padded 144->160; 336 B rows -> 2-way
__global__ __launch_bounds__(576) void attn_kernel(
    const bf16_t* __restrict__ qkv, const float* __restrict__ mask,
    const float* __restrict__ bias_full, bf16_t* __restrict__ attn_o) {
    __shared__ bf16_t smem[176 * PP];
    bf16_t* Pb = smem;                   // [144][PP]
    bf16_t* Vt = smem + 144 * PP;        // [32][PP]
    bf16_t* Ks = smem;                   // [144][KP], dead before P is written

    const int tid = threadIdx.x;
    const int bid = blockIdx.x;
    const int wi = bid / NHEADS;
    const int h = bid % NHEADS;
    const int gb = (wi / WWINS) * NHEADS + h;     // bias group (nw*6+h)
    const bf16_t* base = qkv + (size_t)wi * (LQ * 576);

    {   // stage K and V^T: 576 threads, one (row, 8-chunk) each
        int l = tid >> 2, sg = (tid & 3) * 8;
        const bf16_t* p = base + l * 576 + 192 + h * HD + sg;   // K
        bf16x8 vk = *(const bf16x8*)(p);
        bf16x8 vv = *(const bf16x8*)(p + 192);                  // V
        *(bf16x8*)&Ks[l * KP + sg] = vk;
#pragma unroll
        for (int j = 0; j < 8; ++j) Vt[(sg + j) * PP + l] = vv[j];
    }
    if (tid < 512) Vt[(tid >> 4) * PP + 144 + (tid & 15)] = (bf16_t)0.f;  // Vt tail

    const int lane = tid & 63;
    const int wid = tid >> 6;            // 0..8, wave owns q rows [wid*16, wid*16+16)
    const int l15 = lane & 15;
    const int g = lane >> 4;
    const int q = wid * 16 + l15;        // this lane's q row

    // Q fragment straight from global (B-operand layout = contiguous bf16x8)
    bf16x8 qf = *(const bf16x8*)(base + q * 576 + h * HD + 8 * g);
    __syncthreads();

    f32x4 acc[9];
#pragma unroll
    for (int mt = 0; mt < 9; ++mt) acc[mt] = (f32x4){0.f, 0.f, 0.f, 0.f};
#pragma unroll
    for (int mt = 0; mt < 9; ++mt) {
        bf16x8 kf = *(const bf16x8*)&Ks[(mt * 16 + l15) * KP + 8 * g];
        acc[mt] = __builtin_amdgcn_mfma_f32_16x16x32_bf16(kf, qf, acc[mt], 0, 0, 0);
    }
    // lane holds S^T: q fixed, m = mt*16 + 4g + r
    {
        const f32x4* brow = (const f32x4*)(bias_full + ((size_t)gb * LQ + q) * LQ);
        const f32x4* mrow = (const f32x4*)(mask + ((size_t)wi * LQ + q) * LQ);
#pragma unroll
        for (int mt = 0; mt < 9; ++mt)
            acc[mt] += brow[mt * 4 + g] + mrow[mt * 4 + g];
    }
    __syncthreads();    // everyone done reading Ks before P overwrites

    {   // softmax over this lane's q row (144 vals split across g-groups)
        float mx = -3.0e38f;
#pragma unroll
        for (int mt = 0; mt < 9; ++mt)
#pragma unroll
            for (int r = 0; r < 4; ++r) mx = fmaxf(mx, acc[mt][r]);
        mx = fmaxf(mx, __shfl_xor(mx, 16));
        mx = fmaxf(mx, __shfl_xor(mx, 32));
        float sum = 0.f;
#pragma unroll
        for (int mt = 0; mt < 9; ++mt)
#pragma unroll
            for (int r = 0; r < 4; ++r) {
                float e = __expf(acc[mt][r] - mx);
                acc[mt][r] = e;
                sum += e;
            }
        sum += __shfl_xor(sum, 16);
        sum += __shfl_xor(sum, 32);
        float inv = 1.f / sum;
#pragma unroll
        for (int mt = 0; mt < 9; ++mt) {
            bf16x4 pk;
#pragma unroll
            for (int r = 0; r < 4; ++r) pk[r] = (bf16_t)(acc[mt][r] * inv);
            *(bf16x4*)&Pb[q * PP + mt * 16 + 4 * g] = pk;
        }
    }
    {   // zero P tail m=144..159 for this wave's 16 rows (64 lanes x bf16x4)
        bf16x4 z;
#pragma unroll
        for (int r = 0; r < 4; ++r) z[r] = (bf16_t)0.f;
        int row = wid * 16 + (lane >> 2);
        *(bf16x4*)&Pb[row * PP + 144 + (lane & 3) * 4] = z;
    }
    __syncthreads();

    // PV: out^T[d][q] = sum_m V^T[d][m] * P^T[m][q], 5 m-chunks of 32 (padded)
    f32x4 o[2];
#pragma unroll
    for (int dt = 0; dt < 2; ++dt) o[dt] = (f32x4){0.f, 0.f, 0.f, 0.f};
#pragma unroll
    for (int mc = 0; mc < 5; ++mc) {
        bf16x8 bp = *(const bf16x8*)&Pb[q * PP + mc * 32 + 8 * g];
#pragma unroll
        for (int dt = 0; dt < 2; ++dt) {
            bf16x8 av = *(const bf16x8*)&Vt[(dt * 16 + l15) * PP + mc * 32 + 8 * g];
            o[dt] = __builtin_amdgcn_mfma_f32_16x16x32_bf16(av, bp, o[dt], 0, 0, 0);
        }
    }
    // C layout: q-col = l15 (matches this lane's q), d row = dt*16 + 4g + r
#pragma unroll
    for (int dt = 0; dt < 2; ++dt) {
        bf16x4 pk;
#pragma unroll
        for (int r = 0; r < 4; ++r) pk[r] = (bf16_t)o[dt][r];
        *(bf16x4*)(attn_o + ((size_t)wi * LQ + q) * CDIM + h * HD + dt * 16 + 4 * g) = pk;
    }
}

// ---------------- GEMM2: out = attn_o @ W2 + b2 (fp32 out) ----------------
__global__ __launch_bounds__(256) void gemm2_kernel(
    const bf16_t* __restrict__ A, const bf16_t* __restrict__ W2t,
    const float* __restrict__ b2, float* __restrict__ out) {
    __shared__ bf16_t As[128 * 72];
    __shared__ bf16_t Bs[64 * 72];
    const int tid = threadIdx.x;
    const int row0 = blockIdx.x * 128;
    const int n0 = blockIdx.y * 64;
    const int lane = tid & 63, wid = tid >> 6;
    const int wr = wid >> 1, wc = wid & 1;
    const int l15 = lane & 15, g = lane >> 4;

    f32x4 acc[4][2];
#pragma unroll
    for (int a = 0; a < 4; ++a)
#pragma unroll
        for (int b = 0; b < 2; ++b) acc[a][b] = (f32x4){0.f, 0.f, 0.f, 0.f};

    for (int kk = 0; kk < 3; ++kk) {
        {
            int row = tid >> 1, half = tid & 1;
            const bf16_t* src = A + (size_t)(row0 + row) * 192 + kk * 64 + half * 32;
            bf16_t* dst = &As[row * 72 + half * 32];
            bf16x8 v0 = ((const bf16x8*)src)[0];
            bf16x8 v1 = ((const bf16x8*)src)[1];
            bf16x8 v2 = ((const bf16x8*)src)[2];
            bf16x8 v3 = ((const bf16x8*)src)[3];
            *(bf16x8*)(dst) = v0; *(bf16x8*)(dst + 8) = v1;
            *(bf16x8*)(dst + 16) = v2; *(bf16x8*)(dst + 24) = v3;
        }
        {
            int n = tid >> 2, qtr = tid & 3;
            const bf16_t* src = W2t + (size_t)(n0 + n) * 192 + kk * 64 + qtr * 16;
            bf16x8 v0 = ((const bf16x8*)src)[0];
            bf16x8 v1 = ((const bf16x8*)src)[1];
            *(bf16x8*)&Bs[n * 72 + qtr * 16] = v0;
            *(bf16x8*)&Bs[n * 72 + qtr * 16 + 8] = v1;
        }
        __syncthreads();
#pragma unroll
        for (int ks = 0; ks < 2; ++ks) {
            bf16x8 af[4], bfr[2];
#pragma unroll
            for (int rt = 0; rt < 4; ++rt)
                af[rt] = *(const bf16x8*)&As[(wr * 64 + rt * 16 + l15) * 72 + ks * 32 + 8 * g];
#pragma unroll
            for (int ct = 0; ct < 2; ++ct)
                bfr[ct] = *(const bf16x8*)&Bs[(wc * 32 + ct * 16 + l15) * 72 + ks * 32 + 8 * g];
#pragma unroll
            for (int rt = 0; rt < 4; ++rt)
#pragma unroll
                for (int ct = 0; ct < 2; ++ct)
                    acc[rt][ct] = __builtin_amdgcn_mfma_f32_16x16x32_bf16(af[rt], bfr[ct], acc[rt][ct], 0, 0, 0);
        }
        __syncthreads();
    }
#pragma unroll
    for (int ct = 0; ct < 2; ++ct) {
        int n = n0 + wc * 32 + ct * 16 + l15;
        float bv = b2[n];
#pragma unroll
        for (int rt = 0; rt < 4; ++rt) {
#pragma unroll
            for (int r = 0; r < 4; ++r) {
                int m = row0 + wr * 64 + rt * 16 + 4 * g + r;
                out[(size_t)m * 192 + n] = acc[rt][ct][r] + bv;
            }
        }
    }
}

// ---------------- launch ----------------
extern "C" void kernel_launch(void* const* d_in, const int* in_sizes, int n_in,
                              void* d_out, int out_size, void* d_ws, size_t ws_size,
                              hipStream_t stream) {
    const float* x = (const float*)d_in[0];
    const float* mask = (const float*)d_in[1];
    const float* W1 = (const float*)d_in[2];
    const float* b1 = (const float*)d_in[3];
    const float* W2 = (const float*)d_in[4];
    const float* b2 = (const float*)d_in[5];
    const float* table = (const float*)d_in[6];
    const int* pi = (const int*)d_in[7];
    float* out = (float*)d_out;

    char* ws = (char*)d_ws;
    bf16_t* qkv = (bf16_t*)(ws + OFF_QKV);
    bf16_t* attn_o = (bf16_t*)(ws + OFF_ATTN);
    float* bias_full = (float*)(ws + OFF_BIAS);
    bf16_t* w1t = (bf16_t*)(ws + OFF_W1T);
    bf16_t* w2t = (bf16_t*)(ws + OFF_W2T);

    prep_w_kernel<<<dim3(432), dim3(256), 0, stream>>>(W1, W2, w1t, w2t);
    bias_gather_kernel<<<dim3(31104), dim3(256), 0, stream>>>(table, pi, bias_full);
    gemm1_kernel<<<dim3(1080, 9), dim3(256), 0, stream>>>(x, w1t, b1, qkv);
    attn_kernel<<<dim3(5760), dim3(576), 0, stream>>>(qkv, mask, bias_full, attn_o);
    gemm2_kernel<<<dim3(1080, 3), dim3(256), 0, stream>>>(attn_o, w2t, b2, out);
}